// Round 2
// baseline (1130.232 us; speedup 1.0000x reference)
//
#include <hip/hip_runtime.h>

// Problem constants (reference hardcodes B=16, S=64)
#define BATCH 16
#define HW    64
#define PPB   (HW * HW)          // 4096 pixels per batch image
#define NPIX  (BATCH * PPB)      // 65536 total pixels
#define NELEM (NPIX * 4)         // 262144 loss terms (4 taps per pixel)

__global__ void zero_out_kernel(float* out) {
    out[0] = 0.0f;
}

// One thread per (pixel, tap): 262144 threads = 4096 waves = 16 waves/CU,
// each thread issues exactly ONE scattered corr load -> 4x latency hiding
// vs the 1-pixel/4-loads version (4 waves/CU).
__global__ __launch_bounds__(256) void smpl_loss_kernel(
        const float* __restrict__ corr,   // [B, 4096, 4096]
        const float* __restrict__ flow,   // [B, 2, 64, 64]
        const float* __restrict__ vis,    // [B, 1, 64, 64]
        float* __restrict__ out) {
    const int t   = blockIdx.x * blockDim.x + threadIdx.x;  // 0..262143
    const int tap = t & 3;        // (ox,oy) = (0,0),(0,1),(1,0),(1,1)
    const int pix = t >> 2;       // 0..65535
    const int b = pix >> 12;      // / 4096
    const int p = pix & 4095;     // y*64 + x

    // Lanes tap=0..3 of a pixel read the same flow/vis addrs -> broadcast.
    const float gxv = flow[(size_t)(b * 2 + 0) * PPB + p];
    const float gyv = flow[(size_t)(b * 2 + 1) * PPB + p];
    const float v   = vis[(size_t)b * PPB + p];

    const float gx = (gxv + 1.0f) * 31.5f;   // (w-1)/2
    const float gy = (gyv + 1.0f) * 31.5f;
    const float fx = floorf(gx);
    const float fy = floorf(gy);

    const float ax = fx + 1.0f - gx;   // x low-side residual
    const float bx = gx - fx;
    const float ay = fy + 1.0f - gy;   // y low-side residual
    const float by = gy - fy;

    const int ox = tap >> 1;  // applied to fy
    const int oy = tap & 1;   // applied to fx
    const float wt = (ox ? by : ay) * (oy ? bx : ax);

    const float xi = fminf(fmaxf(fy + (float)ox, 0.0f), 63.0f);
    const float yi = fminf(fmaxf(fx + (float)oy, 0.0f), 63.0f);
    const int idx = (int)(xi * 64.0f + yi);

    const float g = corr[(size_t)pix * (size_t)PPB + (size_t)idx];
    float s = fabsf(g * v - wt * v);

    // wave-64 reduction
#pragma unroll
    for (int o = 32; o > 0; o >>= 1) s += __shfl_down(s, o, 64);

    __shared__ float lds[4];  // 256 threads / 64 = 4 waves
    const int lane = threadIdx.x & 63;
    const int wave = threadIdx.x >> 6;
    if (lane == 0) lds[wave] = s;
    __syncthreads();
    if (threadIdx.x == 0) {
        float tt = (lds[0] + lds[1]) + (lds[2] + lds[3]);
        atomicAdd(out, tt * (1.0f / (float)NELEM));
    }
}

extern "C" void kernel_launch(void* const* d_in, const int* in_sizes, int n_in,
                              void* d_out, int out_size, void* d_ws, size_t ws_size,
                              hipStream_t stream) {
    const float* corr = (const float*)d_in[0];  // [16, 4096, 4096]
    const float* flow = (const float*)d_in[1];  // [16, 2, 64, 64]
    const float* vis  = (const float*)d_in[2];  // [16, 1, 64, 64]
    float* out = (float*)d_out;                 // scalar

    zero_out_kernel<<<1, 1, 0, stream>>>(out);
    smpl_loss_kernel<<<NELEM / 256, 256, 0, stream>>>(corr, flow, vis, out);
}